// Round 1
// baseline (1256.714 us; speedup 1.0000x reference)
//
#include <hip/hip_runtime.h>
#include <math.h>

#define BB 8
#define CC 128
#define N0 4096
#define MSGN 4
#define NTOT 4100
#define IMG 64

// ---------------- workspace layout (floats) ----------------
#define OFF_WQT    0
#define OFF_KV1T   (OFF_WQT + 16384)
#define OFF_KV2T   (OFF_KV1T + 16384)
#define OFF_PROJT  (OFF_KV2T + 16384)
#define OFF_WT1    (OFF_PROJT + 16384)
#define OFF_WT2    (OFF_WT1 + 262144)
#define OFF_QBUF   (OFF_WT2 + 65536)
#define OFF_SR1    (OFF_QBUF + 4198400)   // 8*260*128
#define OFF_XK1    (OFF_SR1 + 266240)
#define OFF_SR2    (OFF_XK1 + 266240)     // 8*1028*128
#define OFF_XK2    (OFF_SR2 + 1052672)
#define OFF_KV1O   (OFF_XK2 + 1052672)
#define OFF_KV2O   (OFF_KV1O + 266240)
#define OFF_VM1    (OFF_KV2O + 1052672)   // 8*260*64
#define OFF_VM2    (OFF_VM1 + 133120)     // 8*1028*64
#define OFF_XCAT   (OFF_VM2 + 526336)

// ---------------- weight prep: transposes ----------------
__global__ void prep_weights(const float* __restrict__ Wq, const float* __restrict__ kv1,
                             const float* __restrict__ kv2, const float* __restrict__ proj,
                             const float* __restrict__ sr1w, const float* __restrict__ sr2w,
                             float* __restrict__ ws) {
    int idx = blockIdx.x * blockDim.x + threadIdx.x;
    if (idx < 4 * 16384) {
        int seg = idx >> 14;
        int l = idx & 16383;
        int c = l >> 7, o = l & 127;          // dest [c][o]
        const float* src = (seg == 0) ? Wq : (seg == 1) ? kv1 : (seg == 2) ? kv2 : proj;
        float* dst = ws + ((seg == 0) ? OFF_WQT : (seg == 1) ? OFF_KV1T : (seg == 2) ? OFF_KV2T : OFF_PROJT);
        dst[l] = src[o * 128 + c];
    } else if (idx < 4 * 16384 + 262144) {
        int l = idx - 4 * 16384;
        int o = l & 127;
        int kp = l >> 7;
        int c = kp & 127;
        int ij = kp >> 7;                      // ij = i*4+j
        ws[OFF_WT1 + l] = sr1w[(o * 128 + c) * 16 + ij];
    } else if (idx < 4 * 16384 + 262144 + 65536) {
        int l = idx - 4 * 16384 - 262144;
        int o = l & 127;
        int kp = l >> 7;
        int c = kp & 127;
        int ij = kp >> 7;                      // ij = i*2+j
        ws[OFF_WT2 + l] = sr2w[(o * 128 + c) * 4 + ij];
    }
}

// ---------------- generic 128x128 gemm (rows of 128) ----------------
// mode 0: input = concat(x,msg) rows, output = plain row buffer (qproj)
// mode 1: input = rowbuf, output = plain row buffer (kv)
// mode 2: input = rowbuf (xcat), residual = concat(x,msg), output = d_out (split)
__global__ __launch_bounds__(256) void gemm128(
    const float* __restrict__ rowbuf, const float* __restrict__ x,
    const float* __restrict__ msg, const float* __restrict__ Wt,
    const float* __restrict__ bias, float* __restrict__ out, int mode, int nrows) {
    __shared__ float xs[16 * 128];
    int tid = threadIdx.x;
    int row0 = blockIdx.x * 16;
    #pragma unroll
    for (int t = 0; t < 8; ++t) {
        int idx = tid + t * 256;
        int rl = idx >> 7, c = idx & 127;
        int row = row0 + rl;
        float v = 0.f;
        if (row < nrows) {
            const float* p;
            if (mode == 1 || mode == 2) p = rowbuf + (size_t)row * 128;
            else {
                int b = row / NTOT, n = row % NTOT;
                p = (n < N0) ? (x + ((size_t)b * N0 + n) * 128)
                             : (msg + ((size_t)b * MSGN + (n - N0)) * 128);
            }
            v = p[c];
        }
        xs[idx] = v;
    }
    __syncthreads();
    int chb = (tid & 15) * 8;
    int rl = tid >> 4;
    float acc[8];
    #pragma unroll
    for (int i = 0; i < 8; ++i) acc[i] = 0.f;
    #pragma unroll 4
    for (int c = 0; c < 128; ++c) {
        float xv = xs[rl * 128 + c];
        const float4* wp = (const float4*)(Wt + c * 128 + chb);
        float4 w0 = wp[0], w1 = wp[1];
        acc[0] += xv * w0.x; acc[1] += xv * w0.y; acc[2] += xv * w0.z; acc[3] += xv * w0.w;
        acc[4] += xv * w1.x; acc[5] += xv * w1.y; acc[6] += xv * w1.z; acc[7] += xv * w1.w;
    }
    int row = row0 + rl;
    if (row >= nrows) return;
    float res[8];
    #pragma unroll
    for (int i = 0; i < 8; ++i) res[i] = acc[i] + bias[chb + i];
    if (mode == 2) {
        int b = row / NTOT, n = row % NTOT;
        const float* rp;
        float* dst;
        if (n < N0) {
            rp = x + ((size_t)b * N0 + n) * 128 + chb;
            dst = out + ((size_t)b * N0 + n) * 128 + chb;
        } else {
            rp = msg + ((size_t)b * MSGN + (n - N0)) * 128 + chb;
            dst = out + (size_t)BB * N0 * 128 + ((size_t)b * MSGN + (n - N0)) * 128 + chb;
        }
        #pragma unroll
        for (int i = 0; i < 8; ++i) res[i] += rp[i];
        float4* d4 = (float4*)dst;
        d4[0] = make_float4(res[0], res[1], res[2], res[3]);
        d4[1] = make_float4(res[4], res[5], res[6], res[7]);
    } else {
        float4* d4 = (float4*)(out + (size_t)row * 128 + chb);
        d4[0] = make_float4(res[0], res[1], res[2], res[3]);
        d4[1] = make_float4(res[4], res[5], res[6], res[7]);
    }
}

// ---------------- SR patch-conv as gemm (k' = ij*128 + c) ----------------
// grid: (ceil(Lm/16), B). 16 token-rows per block, all 128 outputs.
// msg tokens: patch = msg vector broadcast over ij (== einsum with summed weights).
__global__ __launch_bounds__(256) void srconv(
    const float* __restrict__ x, const float* __restrict__ msg,
    const float* __restrict__ Wt, const float* __restrict__ bias,
    float* __restrict__ outbuf, int s, int Wr, int L, int KK, int Lm) {
    __shared__ float xs[16 * 128];
    int tid = threadIdx.x;
    int b = blockIdx.y;
    int t0 = blockIdx.x * 16;
    int chb = (tid & 15) * 8;
    int rl = tid >> 4;
    float acc[8];
    #pragma unroll
    for (int i = 0; i < 8; ++i) acc[i] = 0.f;
    for (int ij = 0; ij < KK; ++ij) {
        int ki = ij / s, kj = ij % s;
        __syncthreads();
        #pragma unroll
        for (int t = 0; t < 8; ++t) {
            int idx = tid + t * 256;
            int r = idx >> 7, c = idx & 127;
            int tok = t0 + r;
            float v = 0.f;
            if (tok < L) {
                int hr = tok / Wr, wr = tok % Wr;
                int pix = (hr * s + ki) * IMG + (wr * s + kj);
                v = x[((size_t)b * N0 + pix) * 128 + c];
            } else if (tok < Lm) {
                v = msg[((size_t)b * MSGN + (tok - L)) * 128 + c];
            }
            xs[idx] = v;
        }
        __syncthreads();
        const float* Wc = Wt + (size_t)ij * 128 * 128;
        #pragma unroll 4
        for (int c = 0; c < 128; ++c) {
            float xv = xs[rl * 128 + c];
            const float4* wp = (const float4*)(Wc + c * 128 + chb);
            float4 w0 = wp[0], w1 = wp[1];
            acc[0] += xv * w0.x; acc[1] += xv * w0.y; acc[2] += xv * w0.z; acc[3] += xv * w0.w;
            acc[4] += xv * w1.x; acc[5] += xv * w1.y; acc[6] += xv * w1.z; acc[7] += xv * w1.w;
        }
    }
    int tok = t0 + rl;
    if (tok >= Lm) return;
    float4* d4 = (float4*)(outbuf + ((size_t)b * Lm + tok) * 128 + chb);
    d4[0] = make_float4(acc[0] + bias[chb + 0], acc[1] + bias[chb + 1],
                        acc[2] + bias[chb + 2], acc[3] + bias[chb + 3]);
    d4[1] = make_float4(acc[4] + bias[chb + 4], acc[5] + bias[chb + 5],
                        acc[6] + bias[chb + 6], acc[7] + bias[chb + 7]);
}

// ---------------- LayerNorm + exact GELU (1 wave per row, 4 rows/block) ----------------
__global__ __launch_bounds__(256) void ln_gelu(
    const float* __restrict__ in, const float* __restrict__ g,
    const float* __restrict__ be, float* __restrict__ outp, int nrows) {
    int wave = threadIdx.x >> 6, lane = threadIdx.x & 63;
    int row = blockIdx.x * 4 + wave;
    if (row >= nrows) return;
    const float* p = in + (size_t)row * 128;
    float a = p[lane], b2 = p[lane + 64];
    float s = a + b2;
    #pragma unroll
    for (int off = 32; off; off >>= 1) s += __shfl_down(s, off);
    s = __shfl(s, 0);
    float mu = s * (1.f / 128.f);
    float da = a - mu, db = b2 - mu;
    float q = da * da + db * db;
    #pragma unroll
    for (int off = 32; off; off >>= 1) q += __shfl_down(q, off);
    q = __shfl(q, 0);
    float rs = rsqrtf(q * (1.f / 128.f) + 1e-5f);
    float y0 = da * rs * g[lane] + be[lane];
    float y1 = db * rs * g[lane + 64] + be[lane + 64];
    y0 = 0.5f * y0 * (1.f + erff(y0 * 0.70710678118654752f));
    y1 = 0.5f * y1 * (1.f + erff(y1 * 0.70710678118654752f));
    float* op = outp + (size_t)row * 128;
    op[lane] = y0;
    op[lane + 64] = y1;
}

// ---------------- V fixup: depthwise 3x3 on spatial V, doubling on msg V ----------------
// vm layout [b][n][64], ch = h2*32 + d
__global__ void vmod_kernel(const float* __restrict__ kv, const float* __restrict__ lcw,
                            const float* __restrict__ lcb, float* __restrict__ vm,
                            int Wr, int L, int Lm) {
    int idx = blockIdx.x * blockDim.x + threadIdx.x;
    int total = BB * Lm * 64;
    if (idx >= total) return;
    int ch = idx & 63;
    int rest = idx >> 6;
    int n = rest % Lm;
    int b = rest / Lm;
    int Hr = L / Wr;
    const float* kvb = kv + (size_t)b * Lm * 128;
    float v = kvb[(size_t)n * 128 + 64 + ch];
    float add;
    if (n < L) {
        int hr = n / Wr, wr = n % Wr;
        float sum = lcb[ch];
        #pragma unroll
        for (int ki = 0; ki < 3; ++ki)
            #pragma unroll
            for (int kj = 0; kj < 3; ++kj) {
                int y = hr + ki - 1, xx = wr + kj - 1;
                if ((unsigned)y < (unsigned)Hr && (unsigned)xx < (unsigned)Wr)
                    sum += lcw[ch * 9 + ki * 3 + kj] * kvb[((size_t)y * Wr + xx) * 128 + 64 + ch];
            }
        add = sum;
    } else {
        add = v;   // msg tokens: v_add = v  => v_new = 2v
    }
    vm[idx] = v + add;
}

// ---------------- attention: 1 thread/query, online softmax over 32-key chunks ----------------
__global__ __launch_bounds__(256) void attn_kernel(
    const float* __restrict__ qbuf, const float* __restrict__ kv,
    const float* __restrict__ vm, float* __restrict__ xcat, int Lm, int branch) {
    __shared__ float Ks[32 * 32];
    __shared__ float Vs[32 * 32];
    int tid = threadIdx.x;
    int b = blockIdx.y;
    int h2 = blockIdx.z;
    int n = blockIdx.x * 256 + tid;
    bool valid = n < NTOT;
    int hg = branch * 2 + h2;
    float q[32];
    if (valid) {
        const float4* qp = (const float4*)(qbuf + ((size_t)b * NTOT + n) * 128 + hg * 32);
        #pragma unroll
        for (int i = 0; i < 8; ++i) {
            float4 v4 = qp[i];
            q[4 * i] = v4.x; q[4 * i + 1] = v4.y; q[4 * i + 2] = v4.z; q[4 * i + 3] = v4.w;
        }
    }
    float m_run = -1e30f, l_run = 0.f;
    float acc[32];
    #pragma unroll
    for (int i = 0; i < 32; ++i) acc[i] = 0.f;
    const float scale = 0.17677669529663687f;   // 1/sqrt(32)
    int nchunks = (Lm + 31) / 32;
    for (int ck = 0; ck < nchunks; ++ck) {
        int k0 = ck * 32;
        __syncthreads();
        #pragma unroll
        for (int t = 0; t < 4; ++t) {
            int idx = tid + t * 256;
            int kl = idx >> 5, d = idx & 31;
            int kn = k0 + kl;
            float kvv = 0.f, vvv = 0.f;
            if (kn < Lm) {
                kvv = kv[((size_t)b * Lm + kn) * 128 + h2 * 32 + d];
                vvv = vm[((size_t)b * Lm + kn) * 64 + h2 * 32 + d];
            }
            Ks[idx] = kvv;
            Vs[idx] = vvv;
        }
        __syncthreads();
        if (!valid) continue;
        int nv = min(32, Lm - k0);
        float s[32];
        float cmax = -1e30f;
        #pragma unroll
        for (int kk = 0; kk < 32; ++kk) {
            if (kk < nv) {
                const float4* kp = (const float4*)(Ks + kk * 32);
                float dot = 0.f;
                #pragma unroll
                for (int i = 0; i < 8; ++i) {
                    float4 k4 = kp[i];
                    dot += q[4 * i] * k4.x + q[4 * i + 1] * k4.y +
                           q[4 * i + 2] * k4.z + q[4 * i + 3] * k4.w;
                }
                s[kk] = dot * scale;
                cmax = fmaxf(cmax, s[kk]);
            }
        }
        float mnew = fmaxf(m_run, cmax);
        float fac = expf(m_run - mnew);
        l_run *= fac;
        #pragma unroll
        for (int i = 0; i < 32; ++i) acc[i] *= fac;
        #pragma unroll
        for (int kk = 0; kk < 32; ++kk) {
            if (kk < nv) {
                float p = expf(s[kk] - mnew);
                l_run += p;
                const float4* vp = (const float4*)(Vs + kk * 32);
                #pragma unroll
                for (int i = 0; i < 8; ++i) {
                    float4 v4 = vp[i];
                    acc[4 * i] += p * v4.x; acc[4 * i + 1] += p * v4.y;
                    acc[4 * i + 2] += p * v4.z; acc[4 * i + 3] += p * v4.w;
                }
            }
        }
        m_run = mnew;
    }
    if (!valid) return;
    float inv = 1.f / l_run;
    float4* op = (float4*)(xcat + ((size_t)b * NTOT + n) * 128 + branch * 64 + h2 * 32);
    #pragma unroll
    for (int i = 0; i < 8; ++i)
        op[i] = make_float4(acc[4 * i] * inv, acc[4 * i + 1] * inv,
                            acc[4 * i + 2] * inv, acc[4 * i + 3] * inv);
}

extern "C" void kernel_launch(void* const* d_in, const int* in_sizes, int n_in,
                              void* d_out, int out_size, void* d_ws, size_t ws_size,
                              hipStream_t stream) {
    const float* x     = (const float*)d_in[0];
    const float* msg   = (const float*)d_in[1];
    const float* Wq    = (const float*)d_in[2];
    const float* bq    = (const float*)d_in[3];
    const float* sr1w  = (const float*)d_in[4];
    const float* sr1b  = (const float*)d_in[5];
    const float* ln1g  = (const float*)d_in[6];
    const float* ln1b  = (const float*)d_in[7];
    const float* sr2w  = (const float*)d_in[8];
    const float* sr2b  = (const float*)d_in[9];
    const float* ln2g  = (const float*)d_in[10];
    const float* ln2b  = (const float*)d_in[11];
    const float* kv1w  = (const float*)d_in[12];
    const float* kv1b  = (const float*)d_in[13];
    const float* kv2w  = (const float*)d_in[14];
    const float* kv2b  = (const float*)d_in[15];
    const float* lc1w  = (const float*)d_in[16];
    const float* lc1b  = (const float*)d_in[17];
    const float* lc2w  = (const float*)d_in[18];
    const float* lc2b  = (const float*)d_in[19];
    const float* projw = (const float*)d_in[20];
    const float* projb = (const float*)d_in[21];
    float* ws  = (float*)d_ws;
    float* out = (float*)d_out;

    float* Wq_t   = ws + OFF_WQT;
    float* kv1_t  = ws + OFF_KV1T;
    float* kv2_t  = ws + OFF_KV2T;
    float* proj_t = ws + OFF_PROJT;
    float* Wt1    = ws + OFF_WT1;
    float* Wt2    = ws + OFF_WT2;
    float* qbuf   = ws + OFF_QBUF;
    float* sr1o   = ws + OFF_SR1;
    float* xk1    = ws + OFF_XK1;
    float* sr2o   = ws + OFF_SR2;
    float* xk2    = ws + OFF_XK2;
    float* kv1o   = ws + OFF_KV1O;
    float* kv2o   = ws + OFF_KV2O;
    float* vm1    = ws + OFF_VM1;
    float* vm2    = ws + OFF_VM2;
    float* xcat   = ws + OFF_XCAT;

    prep_weights<<<1536, 256, 0, stream>>>(Wq, kv1w, kv2w, projw, sr1w, sr2w, ws);

    // q projection over concat(x, msg): rows = 8*4100 = 32800
    gemm128<<<2050, 256, 0, stream>>>(nullptr, x, msg, Wq_t, bq, qbuf, 0, BB * NTOT);

    // ---- branch 1 (stride 4, L=256, Lm=260) ----
    srconv<<<dim3(17, 8), 256, 0, stream>>>(x, msg, Wt1, sr1b, sr1o, 4, 16, 256, 16, 260);
    ln_gelu<<<520, 256, 0, stream>>>(sr1o, ln1g, ln1b, xk1, BB * 260);
    gemm128<<<130, 256, 0, stream>>>(xk1, nullptr, nullptr, kv1_t, kv1b, kv1o, 1, BB * 260);
    vmod_kernel<<<520, 256, 0, stream>>>(kv1o, lc1w, lc1b, vm1, 16, 256, 260);
    attn_kernel<<<dim3(17, 8, 2), 256, 0, stream>>>(qbuf, kv1o, vm1, xcat, 260, 0);

    // ---- branch 2 (stride 2, L=1024, Lm=1028) ----
    srconv<<<dim3(65, 8), 256, 0, stream>>>(x, msg, Wt2, sr2b, sr2o, 2, 32, 1024, 4, 1028);
    ln_gelu<<<2056, 256, 0, stream>>>(sr2o, ln2g, ln2b, xk2, BB * 1028);
    gemm128<<<514, 256, 0, stream>>>(xk2, nullptr, nullptr, kv2_t, kv2b, kv2o, 1, BB * 1028);
    vmod_kernel<<<2056, 256, 0, stream>>>(kv2o, lc2w, lc2b, vm2, 32, 1024, 1028);
    attn_kernel<<<dim3(17, 8, 2), 256, 0, stream>>>(qbuf, kv2o, vm2, xcat, 1028, 1);

    // final projection + residual, split-write to d_out
    gemm128<<<2050, 256, 0, stream>>>(xcat, x, msg, proj_t, projb, out, 2, BB * NTOT);
}

// Round 2
// 644.150 us; speedup vs baseline: 1.9510x; 1.9510x over previous
//
#include <hip/hip_runtime.h>
#include <math.h>

#define BB 8
#define CC 128
#define N0 4096
#define MSGN 4
#define NTOT 4100
#define IMG 64
#define NPAD 4112
#define QTILES 257

// ---------------- workspace layout (float indices) ----------------
#define OFF_WQT    0
#define OFF_KV1T   (OFF_WQT + 16384)
#define OFF_KV2T   (OFF_KV1T + 16384)
#define OFF_PROJT  (OFF_KV2T + 16384)
#define OFF_WT1    (OFF_PROJT + 16384)
#define OFF_WT2    (OFF_WT1 + 262144)
#define OFF_QH     (OFF_WT2 + 65536)      // fp16: 8*4*4112*32 halves = 2105344 floats
#define OFF_SR1    (OFF_QH + 2105344)
#define OFF_XK1    (OFF_SR1 + 266240)
#define OFF_SR2    (OFF_XK1 + 266240)
#define OFF_XK2    (OFF_SR2 + 1052672)
#define OFF_KV1O   (OFF_XK2 + 1052672)
#define OFF_KV2O   (OFF_KV1O + 266240)
#define OFF_KH1    (OFF_KV2O + 1052672)   // fp16: 8*2*272*32 halves
#define OFF_VT1    (OFF_KH1 + 69632)
#define OFF_KH2    (OFF_VT1 + 69632)      // fp16: 8*2*1040*32 halves
#define OFF_VT2    (OFF_KH2 + 266240)
#define OFF_XCAT   (OFF_VT2 + 266240)

typedef _Float16 half8v __attribute__((ext_vector_type(8)));
typedef _Float16 half4v __attribute__((ext_vector_type(4)));
typedef float f32x4 __attribute__((ext_vector_type(4)));

// ---------------- weight prep: transposes ----------------
__global__ void prep_weights(const float* __restrict__ Wq, const float* __restrict__ kv1,
                             const float* __restrict__ kv2, const float* __restrict__ proj,
                             const float* __restrict__ sr1w, const float* __restrict__ sr2w,
                             float* __restrict__ ws) {
    int idx = blockIdx.x * blockDim.x + threadIdx.x;
    if (idx < 4 * 16384) {
        int seg = idx >> 14;
        int l = idx & 16383;
        int c = l >> 7, o = l & 127;          // dest [c][o]
        const float* src = (seg == 0) ? Wq : (seg == 1) ? kv1 : (seg == 2) ? kv2 : proj;
        float* dst = ws + ((seg == 0) ? OFF_WQT : (seg == 1) ? OFF_KV1T : (seg == 2) ? OFF_KV2T : OFF_PROJT);
        dst[l] = src[o * 128 + c];
    } else if (idx < 4 * 16384 + 262144) {
        int l = idx - 4 * 16384;
        int o = l & 127;
        int kp = l >> 7;
        int c = kp & 127;
        int ij = kp >> 7;
        ws[OFF_WT1 + l] = sr1w[(o * 128 + c) * 16 + ij];
    } else if (idx < 4 * 16384 + 262144 + 65536) {
        int l = idx - 4 * 16384 - 262144;
        int o = l & 127;
        int kp = l >> 7;
        int c = kp & 127;
        int ij = kp >> 7;
        ws[OFF_WT2 + l] = sr2w[(o * 128 + c) * 4 + ij];
    }
}

// zero fp16 Q pad rows (queries 4100..4111)
__global__ void zero_qpad(_Float16* __restrict__ Qh) {
    int idx = blockIdx.x * blockDim.x + threadIdx.x;
    if (idx >= BB * 4 * (NPAD - NTOT) * 32) return;
    int d = idx & 31;
    int rest = idx >> 5;
    int n = NTOT + rest % (NPAD - NTOT);
    int rest2 = rest / (NPAD - NTOT);
    int hg = rest2 & 3;
    int b = rest2 >> 2;
    Qh[((size_t)(b * 4 + hg) * NPAD + n) * 32 + d] = (_Float16)0.f;
}

// ---------------- generic 128x128 gemm (rows of 128) ----------------
// mode 0: input = concat(x,msg), output = fp16 Q buffer [b][hg][NPAD][32]
// mode 1: input = rowbuf, output = plain fp32 row buffer (kv)
// mode 2: input = rowbuf (xcat), residual = concat(x,msg), output = d_out (split)
__global__ __launch_bounds__(256) void gemm128(
    const float* __restrict__ rowbuf, const float* __restrict__ x,
    const float* __restrict__ msg, const float* __restrict__ Wt,
    const float* __restrict__ bias, float* __restrict__ out, int mode, int nrows) {
    __shared__ float xs[16 * 128];
    int tid = threadIdx.x;
    int row0 = blockIdx.x * 16;
    #pragma unroll
    for (int t = 0; t < 8; ++t) {
        int idx = tid + t * 256;
        int rl = idx >> 7, c = idx & 127;
        int row = row0 + rl;
        float v = 0.f;
        if (row < nrows) {
            const float* p;
            if (mode == 1 || mode == 2) p = rowbuf + (size_t)row * 128;
            else {
                int b = row / NTOT, n = row % NTOT;
                p = (n < N0) ? (x + ((size_t)b * N0 + n) * 128)
                             : (msg + ((size_t)b * MSGN + (n - N0)) * 128);
            }
            v = p[c];
        }
        xs[idx] = v;
    }
    __syncthreads();
    int chb = (tid & 15) * 8;
    int rl = tid >> 4;
    float acc[8];
    #pragma unroll
    for (int i = 0; i < 8; ++i) acc[i] = 0.f;
    #pragma unroll 4
    for (int c = 0; c < 128; ++c) {
        float xv = xs[rl * 128 + c];
        const float4* wp = (const float4*)(Wt + c * 128 + chb);
        float4 w0 = wp[0], w1 = wp[1];
        acc[0] += xv * w0.x; acc[1] += xv * w0.y; acc[2] += xv * w0.z; acc[3] += xv * w0.w;
        acc[4] += xv * w1.x; acc[5] += xv * w1.y; acc[6] += xv * w1.z; acc[7] += xv * w1.w;
    }
    int row = row0 + rl;
    if (row >= nrows) return;
    float res[8];
    #pragma unroll
    for (int i = 0; i < 8; ++i) res[i] = acc[i] + bias[chb + i];
    if (mode == 0) {
        int b = row / NTOT, n = row % NTOT;
        _Float16* qh = (_Float16*)out;
        int hg = chb >> 5, d0 = chb & 31;
        _Float16* qp = qh + ((size_t)(b * 4 + hg) * NPAD + n) * 32 + d0;
        #pragma unroll
        for (int i = 0; i < 8; ++i) qp[i] = (_Float16)res[i];
    } else if (mode == 2) {
        int b = row / NTOT, n = row % NTOT;
        const float* rp;
        float* dst;
        if (n < N0) {
            rp = x + ((size_t)b * N0 + n) * 128 + chb;
            dst = out + ((size_t)b * N0 + n) * 128 + chb;
        } else {
            rp = msg + ((size_t)b * MSGN + (n - N0)) * 128 + chb;
            dst = out + (size_t)BB * N0 * 128 + ((size_t)b * MSGN + (n - N0)) * 128 + chb;
        }
        #pragma unroll
        for (int i = 0; i < 8; ++i) res[i] += rp[i];
        float4* d4 = (float4*)dst;
        d4[0] = make_float4(res[0], res[1], res[2], res[3]);
        d4[1] = make_float4(res[4], res[5], res[6], res[7]);
    } else {
        float4* d4 = (float4*)(out + (size_t)row * 128 + chb);
        d4[0] = make_float4(res[0], res[1], res[2], res[3]);
        d4[1] = make_float4(res[4], res[5], res[6], res[7]);
    }
}

// ---------------- SR patch-conv as gemm ----------------
__global__ __launch_bounds__(256) void srconv(
    const float* __restrict__ x, const float* __restrict__ msg,
    const float* __restrict__ Wt, const float* __restrict__ bias,
    float* __restrict__ outbuf, int s, int Wr, int L, int KK, int Lm) {
    __shared__ float xs[16 * 128];
    int tid = threadIdx.x;
    int b = blockIdx.y;
    int t0 = blockIdx.x * 16;
    int chb = (tid & 15) * 8;
    int rl = tid >> 4;
    float acc[8];
    #pragma unroll
    for (int i = 0; i < 8; ++i) acc[i] = 0.f;
    for (int ij = 0; ij < KK; ++ij) {
        int ki = ij / s, kj = ij % s;
        __syncthreads();
        #pragma unroll
        for (int t = 0; t < 8; ++t) {
            int idx = tid + t * 256;
            int r = idx >> 7, c = idx & 127;
            int tok = t0 + r;
            float v = 0.f;
            if (tok < L) {
                int hr = tok / Wr, wr = tok % Wr;
                int pix = (hr * s + ki) * IMG + (wr * s + kj);
                v = x[((size_t)b * N0 + pix) * 128 + c];
            } else if (tok < Lm) {
                v = msg[((size_t)b * MSGN + (tok - L)) * 128 + c];
            }
            xs[idx] = v;
        }
        __syncthreads();
        const float* Wc = Wt + (size_t)ij * 128 * 128;
        #pragma unroll 4
        for (int c = 0; c < 128; ++c) {
            float xv = xs[rl * 128 + c];
            const float4* wp = (const float4*)(Wc + c * 128 + chb);
            float4 w0 = wp[0], w1 = wp[1];
            acc[0] += xv * w0.x; acc[1] += xv * w0.y; acc[2] += xv * w0.z; acc[3] += xv * w0.w;
            acc[4] += xv * w1.x; acc[5] += xv * w1.y; acc[6] += xv * w1.z; acc[7] += xv * w1.w;
        }
    }
    int tok = t0 + rl;
    if (tok >= Lm) return;
    float4* d4 = (float4*)(outbuf + ((size_t)b * Lm + tok) * 128 + chb);
    d4[0] = make_float4(acc[0] + bias[chb + 0], acc[1] + bias[chb + 1],
                        acc[2] + bias[chb + 2], acc[3] + bias[chb + 3]);
    d4[1] = make_float4(acc[4] + bias[chb + 4], acc[5] + bias[chb + 5],
                        acc[6] + bias[chb + 6], acc[7] + bias[chb + 7]);
}

// ---------------- LayerNorm + exact GELU ----------------
__global__ __launch_bounds__(256) void ln_gelu(
    const float* __restrict__ in, const float* __restrict__ g,
    const float* __restrict__ be, float* __restrict__ outp, int nrows) {
    int wave = threadIdx.x >> 6, lane = threadIdx.x & 63;
    int row = blockIdx.x * 4 + wave;
    if (row >= nrows) return;
    const float* p = in + (size_t)row * 128;
    float a = p[lane], b2 = p[lane + 64];
    float s = a + b2;
    #pragma unroll
    for (int off = 32; off; off >>= 1) s += __shfl_down(s, off);
    s = __shfl(s, 0);
    float mu = s * (1.f / 128.f);
    float da = a - mu, db = b2 - mu;
    float q = da * da + db * db;
    #pragma unroll
    for (int off = 32; off; off >>= 1) q += __shfl_down(q, off);
    q = __shfl(q, 0);
    float rs = rsqrtf(q * (1.f / 128.f) + 1e-5f);
    float y0 = da * rs * g[lane] + be[lane];
    float y1 = db * rs * g[lane + 64] + be[lane + 64];
    y0 = 0.5f * y0 * (1.f + erff(y0 * 0.70710678118654752f));
    y1 = 0.5f * y1 * (1.f + erff(y1 * 0.70710678118654752f));
    float* op = outp + (size_t)row * 128;
    op[lane] = y0;
    op[lane + 64] = y1;
}

// ---------------- fused V-fixup + fp16 pack ----------------
// K -> Kh [b][h2][Lmp][32] fp16 ;  v + (dwconv|double) -> Vt [b][h2][32][Lmp] fp16 (transposed)
__global__ void pack_kv(const float* __restrict__ kv, const float* __restrict__ lcw,
                        const float* __restrict__ lcb, _Float16* __restrict__ Kh,
                        _Float16* __restrict__ Vt, int Wr, int L, int Lm, int Lmp) {
    int idx = blockIdx.x * blockDim.x + threadIdx.x;
    int total = BB * Lmp * 64;
    if (idx >= total) return;
    int ch = idx & 63;
    int rest = idx >> 6;
    int n = rest % Lmp;
    int b = rest / Lmp;
    int h2 = ch >> 5, d = ch & 31;
    int Hr = L / Wr;
    float kval = 0.f, vnew = 0.f;
    if (n < Lm) {
        const float* kvb = kv + (size_t)b * Lm * 128;
        kval = kvb[(size_t)n * 128 + ch];
        float v = kvb[(size_t)n * 128 + 64 + ch];
        float add;
        if (n < L) {
            int hr = n / Wr, wr = n % Wr;
            float sum = lcb[ch];
            #pragma unroll
            for (int ki = 0; ki < 3; ++ki)
                #pragma unroll
                for (int kj = 0; kj < 3; ++kj) {
                    int y = hr + ki - 1, xx = wr + kj - 1;
                    if ((unsigned)y < (unsigned)Hr && (unsigned)xx < (unsigned)Wr)
                        sum += lcw[ch * 9 + ki * 3 + kj] * kvb[((size_t)y * Wr + xx) * 128 + 64 + ch];
                }
            add = sum;
        } else {
            add = v;   // msg tokens: v_add = v  => v_new = 2v
        }
        vnew = v + add;
    }
    Kh[((size_t)(b * 2 + h2) * Lmp + n) * 32 + d] = (_Float16)kval;
    Vt[((size_t)(b * 2 + h2) * 32 + d) * Lmp + n] = (_Float16)vnew;
}

// ---------------- MFMA flash attention (register-only, no LDS) ----------------
// Per wave: one 16-query tile. S^T = K*Q^T via mfma_16x16x32_f16: C/D layout
// (col=lane&15=query, row=quad*4+r=key) == A-operand layout of 16x16x16f16 for P*V.
__global__ __launch_bounds__(256) void attn_mfma(
    const _Float16* __restrict__ Qh, const _Float16* __restrict__ Kh,
    const _Float16* __restrict__ Vt, float* __restrict__ xcat,
    int Lm, int Lmp, int branch) {
    int tid = threadIdx.x;
    int lane = tid & 63, wave = tid >> 6;
    int b = blockIdx.y, h2 = blockIdx.z;
    int tile = blockIdx.x * 4 + wave;
    if (tile >= QTILES) return;
    int n0 = tile * 16;
    int q16 = lane & 15, quad = lane >> 4;
    int hg = branch * 2 + h2;

    half8v qf = *(const half8v*)(Qh + ((size_t)(b * 4 + hg) * NPAD + n0 + q16) * 32 + quad * 8);
    const _Float16* kb = Kh + (size_t)(b * 2 + h2) * Lmp * 32;
    const _Float16* vb = Vt + (size_t)(b * 2 + h2) * 32 * Lmp;

    f32x4 O0 = {0.f, 0.f, 0.f, 0.f}, O1 = {0.f, 0.f, 0.f, 0.f};
    float m_run = -1e30f, l_part = 0.f;
    const float scale = 0.17677669529663687f;   // 1/sqrt(32)
    const f32x4 zf = {0.f, 0.f, 0.f, 0.f};

    for (int k0 = 0; k0 < Lmp; k0 += 16) {
        half8v kf = *(const half8v*)(kb + (size_t)(k0 + q16) * 32 + quad * 8);
        f32x4 s4 = __builtin_amdgcn_mfma_f32_16x16x32_f16(kf, qf, zf, 0, 0, 0);
        float sc[4];
        #pragma unroll
        for (int r = 0; r < 4; ++r) {
            int key = k0 + quad * 4 + r;
            sc[r] = (key < Lm) ? s4[r] * scale : -1e30f;
        }
        float mx = fmaxf(fmaxf(sc[0], sc[1]), fmaxf(sc[2], sc[3]));
        mx = fmaxf(mx, __shfl_xor(mx, 16));
        mx = fmaxf(mx, __shfl_xor(mx, 32));
        float mnew = fmaxf(m_run, mx);
        float alpha = __expf(m_run - mnew);
        m_run = mnew;
        float p[4];
        #pragma unroll
        for (int r = 0; r < 4; ++r) p[r] = __expf(sc[r] - mnew);
        l_part = l_part * alpha + p[0] + p[1] + p[2] + p[3];
        half4v pf;
        #pragma unroll
        for (int r = 0; r < 4; ++r) pf[r] = (_Float16)p[r];
        int kq = k0 + quad * 4;
        half4v v0 = *(const half4v*)(vb + (size_t)q16 * Lmp + kq);
        half4v v1 = *(const half4v*)(vb + (size_t)(16 + q16) * Lmp + kq);
        #pragma unroll
        for (int r = 0; r < 4; ++r) {
            float ar = __shfl(alpha, quad * 4 + r);
            O0[r] *= ar;
            O1[r] *= ar;
        }
        O0 = __builtin_amdgcn_mfma_f32_16x16x16f16(pf, v0, O0, 0, 0, 0);
        O1 = __builtin_amdgcn_mfma_f32_16x16x16f16(pf, v1, O1, 0, 0, 0);
    }

    float l = l_part;
    l += __shfl_xor(l, 16);
    l += __shfl_xor(l, 32);
    float invl = 1.f / l;
    #pragma unroll
    for (int r = 0; r < 4; ++r) {
        float ir = __shfl(invl, quad * 4 + r);
        int n = n0 + quad * 4 + r;
        if (n < NTOT) {
            float* op = xcat + ((size_t)b * NTOT + n) * 128 + branch * 64 + h2 * 32 + q16;
            op[0] = O0[r] * ir;
            op[16] = O1[r] * ir;
        }
    }
}

extern "C" void kernel_launch(void* const* d_in, const int* in_sizes, int n_in,
                              void* d_out, int out_size, void* d_ws, size_t ws_size,
                              hipStream_t stream) {
    const float* x     = (const float*)d_in[0];
    const float* msg   = (const float*)d_in[1];
    const float* Wq    = (const float*)d_in[2];
    const float* bq    = (const float*)d_in[3];
    const float* sr1w  = (const float*)d_in[4];
    const float* sr1b  = (const float*)d_in[5];
    const float* ln1g  = (const float*)d_in[6];
    const float* ln1b  = (const float*)d_in[7];
    const float* sr2w  = (const float*)d_in[8];
    const float* sr2b  = (const float*)d_in[9];
    const float* ln2g  = (const float*)d_in[10];
    const float* ln2b  = (const float*)d_in[11];
    const float* kv1w  = (const float*)d_in[12];
    const float* kv1b  = (const float*)d_in[13];
    const float* kv2w  = (const float*)d_in[14];
    const float* kv2b  = (const float*)d_in[15];
    const float* lc1w  = (const float*)d_in[16];
    const float* lc1b  = (const float*)d_in[17];
    const float* lc2w  = (const float*)d_in[18];
    const float* lc2b  = (const float*)d_in[19];
    const float* projw = (const float*)d_in[20];
    const float* projb = (const float*)d_in[21];
    float* ws  = (float*)d_ws;
    float* out = (float*)d_out;

    float* Wq_t   = ws + OFF_WQT;
    float* kv1_t  = ws + OFF_KV1T;
    float* kv2_t  = ws + OFF_KV2T;
    float* proj_t = ws + OFF_PROJT;
    float* Wt1    = ws + OFF_WT1;
    float* Wt2    = ws + OFF_WT2;
    _Float16* Qh  = (_Float16*)(ws + OFF_QH);
    float* sr1o   = ws + OFF_SR1;
    float* xk1    = ws + OFF_XK1;
    float* sr2o   = ws + OFF_SR2;
    float* xk2    = ws + OFF_XK2;
    float* kv1o   = ws + OFF_KV1O;
    float* kv2o   = ws + OFF_KV2O;
    _Float16* Kh1 = (_Float16*)(ws + OFF_KH1);
    _Float16* Vt1 = (_Float16*)(ws + OFF_VT1);
    _Float16* Kh2 = (_Float16*)(ws + OFF_KH2);
    _Float16* Vt2 = (_Float16*)(ws + OFF_VT2);
    float* xcat   = ws + OFF_XCAT;

    prep_weights<<<1536, 256, 0, stream>>>(Wq, kv1w, kv2w, projw, sr1w, sr2w, ws);
    zero_qpad<<<48, 256, 0, stream>>>(Qh);

    // q projection -> fp16 Q buffer [b][head][NPAD][32]
    gemm128<<<2050, 256, 0, stream>>>(nullptr, x, msg, Wq_t, bq, (float*)Qh, 0, BB * NTOT);

    // ---- branch 1 (stride 4, L=256, Lm=260, Lmp=272) ----
    srconv<<<dim3(17, 8), 256, 0, stream>>>(x, msg, Wt1, sr1b, sr1o, 4, 16, 256, 16, 260);
    ln_gelu<<<520, 256, 0, stream>>>(sr1o, ln1g, ln1b, xk1, BB * 260);
    gemm128<<<130, 256, 0, stream>>>(xk1, nullptr, nullptr, kv1_t, kv1b, kv1o, 1, BB * 260);
    pack_kv<<<544, 256, 0, stream>>>(kv1o, lc1w, lc1b, Kh1, Vt1, 16, 256, 260, 272);
    attn_mfma<<<dim3(65, 8, 2), 256, 0, stream>>>(Qh, Kh1, Vt1, xcat, 260, 272, 0);

    // ---- branch 2 (stride 2, L=1024, Lm=1028, Lmp=1040) ----
    srconv<<<dim3(65, 8), 256, 0, stream>>>(x, msg, Wt2, sr2b, sr2o, 2, 32, 1024, 4, 1028);
    ln_gelu<<<2056, 256, 0, stream>>>(sr2o, ln2g, ln2b, xk2, BB * 1028);
    gemm128<<<514, 256, 0, stream>>>(xk2, nullptr, nullptr, kv2_t, kv2b, kv2o, 1, BB * 1028);
    pack_kv<<<2080, 256, 0, stream>>>(kv2o, lc2w, lc2b, Kh2, Vt2, 32, 1024, 1028, 1040);
    attn_mfma<<<dim3(65, 8, 2), 256, 0, stream>>>(Qh, Kh2, Vt2, xcat, 1028, 1040, 1);

    // final projection + residual, split-write to d_out
    gemm128<<<2050, 256, 0, stream>>>(xcat, x, msg, proj_t, projb, out, 2, BB * NTOT);
}

// Round 3
// 289.723 us; speedup vs baseline: 4.3376x; 2.2233x over previous
//
#include <hip/hip_runtime.h>
#include <math.h>

#define BB 8
#define CC 128
#define N0 4096
#define MSGN 4
#define NTOT 4100
#define IMG 64
#define NPAD 4112
#define QTILES 257

// ---------------- workspace layout (float indices) ----------------
#define OFF_WFQ    0           // 2048 units (8 halves each) = 8192 f
#define OFF_WFKV1  8192
#define OFF_WFKV2  16384
#define OFF_WFPROJ 24576
#define OFF_WFSR1  32768       // K=2048: 131072 f
#define OFF_WFSR2  163840      // K=512:  32768 f
#define OFF_QH     196608      // fp16 8*4*4112*32 = 2105344 f
#define OFF_XA     2301952     // shared: qproj A-frags / attn-out A-frags, 32832*128 h = 2101248 f
#define OFF_XIM    4403200     // im2col A-frags, max 2112*2048 h = 2162688 f
#define OFF_XK1    6565888     // LN+GELU out A-frags 2112*128 h = 135168 f
#define OFF_XK2    6701056     // 8256*128 h = 528384 f
#define OFF_KV1O   7229440     // fp32 8*260*128 = 266240 f
#define OFF_KV2O   7495680     // fp32 8*1028*128 = 1052672 f
#define OFF_KH1    8548352     // fp16 8*2*272*32 = 69632 f
#define OFF_VT1    8617984
#define OFF_KH2    8687616     // fp16 8*2*1040*32 = 266240 f
#define OFF_VT2    8953856
// end: 9220096 floats = 36.9 MB

typedef _Float16 half8v __attribute__((ext_vector_type(8)));
typedef _Float16 half4v __attribute__((ext_vector_type(4)));
typedef float f32x4 __attribute__((ext_vector_type(4)));

// A-frag scalar index for element (m, k), K=out-of-128 only used with Kc=4
__device__ __forceinline__ size_t af_idx(int m, int k, int Kc) {
    return ((size_t)((m >> 4) * Kc + (k >> 5)) * 64 + ((k >> 3) & 3) * 16 + (m & 15)) * 8 + (k & 7);
}

// ---------------- weight prep: swizzle into B-fragment order ----------------
// B-frag unit u = (kc*8 + t)*64 + lane, lane = quad*16 + n15; holds 8 halves j=0..7
// value = W[k = kc*32 + quad*8 + j][n = t*16 + n15]
__global__ void prep_weights(const float* __restrict__ Wq, const float* __restrict__ kv1,
                             const float* __restrict__ kv2, const float* __restrict__ proj,
                             const float* __restrict__ sr1w, const float* __restrict__ sr2w,
                             float* __restrict__ ws) {
    int u = blockIdx.x * blockDim.x + threadIdx.x;   // 49152 units
    int seg, base;
    const float* w = nullptr;
    _Float16* dst;
    if (u < 2048)        { seg = 0; base = u;          w = Wq;   dst = (_Float16*)(ws + OFF_WFQ); }
    else if (u < 4096)   { seg = 0; base = u - 2048;   w = kv1;  dst = (_Float16*)(ws + OFF_WFKV1); }
    else if (u < 6144)   { seg = 0; base = u - 4096;   w = kv2;  dst = (_Float16*)(ws + OFF_WFKV2); }
    else if (u < 8192)   { seg = 0; base = u - 6144;   w = proj; dst = (_Float16*)(ws + OFF_WFPROJ); }
    else if (u < 40960)  { seg = 1; base = u - 8192;   w = sr1w; dst = (_Float16*)(ws + OFF_WFSR1); }
    else if (u < 49152)  { seg = 2; base = u - 40960;  w = sr2w; dst = (_Float16*)(ws + OFF_WFSR2); }
    else return;
    int lane = base & 63;
    int t = (base >> 6) & 7;
    int kc = base >> 9;
    int n = t * 16 + (lane & 15);
    int k0 = kc * 32 + (lane >> 4) * 8;
    half8v val;
    #pragma unroll
    for (int j = 0; j < 8; ++j) {
        int k = k0 + j;
        float v;
        if (seg == 0) v = w[n * 128 + k];                              // linear: W[k][n]=w[n][k]
        else if (seg == 1) v = w[(n * 128 + (k & 127)) * 16 + (k >> 7)]; // sr1: k=ij*128+c
        else v = w[(n * 128 + (k & 127)) * 4 + (k >> 7)];                // sr2
        val[j] = (_Float16)v;
    }
    *(half8v*)(dst + (size_t)base * 8) = val;
}

// ---------------- convert x||msg -> A-frag fp16 (K=128) ----------------
__global__ void convert_x(const float* __restrict__ x, const float* __restrict__ msg,
                          _Float16* __restrict__ Af) {
    int u = blockIdx.x * blockDim.x + threadIdx.x;    // 32832*16 = 525312 units
    if (u >= 525312) return;
    int mlow = u & 15, quadk = (u >> 4) & 3;
    int rest = u >> 6;
    int kc = rest & 3;      // Kc = 4
    int mt = rest >> 2;
    int m = mt * 16 + mlow;
    int c0 = (kc * 4 + quadk) * 8;
    half8v val;
    if (m < BB * NTOT) {
        int b = m / NTOT, n = m - b * NTOT;
        const float* p = (n < N0) ? (x + ((size_t)b * N0 + n) * 128 + c0)
                                  : (msg + ((size_t)b * MSGN + (n - N0)) * 128 + c0);
        #pragma unroll
        for (int j = 0; j < 8; ++j) val[j] = (_Float16)p[j];
    } else {
        #pragma unroll
        for (int j = 0; j < 8; ++j) val[j] = (_Float16)0.f;
    }
    *(half8v*)(Af + (size_t)u * 8) = val;
}

// ---------------- im2col (pure permutation: stride == patch size) ----------------
// rows m = b*Lm + tok; k = ij*128 + c
__global__ void im2col(const float* __restrict__ x, const float* __restrict__ msg,
                       _Float16* __restrict__ Af, int s, int Wr, int L, int Lm,
                       int Kc, int nunits) {
    int u = blockIdx.x * blockDim.x + threadIdx.x;
    if (u >= nunits) return;
    int mlow = u & 15, quadk = (u >> 4) & 3;
    int rest = u >> 6;
    int kc = rest % Kc;
    int mt = rest / Kc;
    int m = mt * 16 + mlow;
    int k0 = (kc * 4 + quadk) * 8;
    half8v val;
    if (m < BB * Lm) {
        int b = m / Lm, tok = m - b * Lm;
        int ij = k0 >> 7, c = k0 & 127;
        const float* p;
        if (tok < L) {
            int hr = tok / Wr, wr = tok - hr * Wr;
            int ki = ij / s, kj = ij - ki * s;
            int pix = (hr * s + ki) * IMG + (wr * s + kj);
            p = x + ((size_t)b * N0 + pix) * 128 + c;
        } else {
            p = msg + ((size_t)b * MSGN + (tok - L)) * 128 + c;
        }
        #pragma unroll
        for (int j = 0; j < 8; ++j) val[j] = (_Float16)p[j];
    } else {
        #pragma unroll
        for (int j = 0; j < 8; ++j) val[j] = (_Float16)0.f;
    }
    *(half8v*)(Af + (size_t)u * 8) = val;
}

// zero fp16 Q pad rows (queries 4100..4111)
__global__ void zero_qpad(_Float16* __restrict__ Qh) {
    int idx = blockIdx.x * blockDim.x + threadIdx.x;
    if (idx >= BB * 4 * (NPAD - NTOT) * 32) return;
    int d = idx & 31;
    int rest = idx >> 5;
    int n = NTOT + rest % (NPAD - NTOT);
    int rest2 = rest / (NPAD - NTOT);
    int hg = rest2 & 3;
    int b = rest2 >> 2;
    Qh[((size_t)(b * 4 + hg) * NPAD + n) * 32 + d] = (_Float16)0.f;
}

// ---------------- unified MFMA gemm: [M x K] * [K x 128] ----------------
// wave: 16 rows x 128 cols, register-only, no LDS.
// mode 0: +bias -> Qh fp16 attention layout
// mode 1: +bias -> fp32 row-major (kv)
// mode 2: +bias, LN(g,b), GELU -> A-frag fp16
// mode 3: +bias, +residual(x,msg) -> d_out split fp32
__global__ __launch_bounds__(256) void gemm_mfma(
    const _Float16* __restrict__ Af, const _Float16* __restrict__ Wf,
    const float* __restrict__ bias, int K, int Mvalid, int mode,
    float* __restrict__ out_f32, _Float16* __restrict__ out_f16,
    const float* __restrict__ ln_g, const float* __restrict__ ln_b,
    const float* __restrict__ x, const float* __restrict__ msg) {
    int lane = threadIdx.x & 63, wave = threadIdx.x >> 6;
    int mt = blockIdx.x * 4 + wave;
    int Kc = K >> 5;
    const half8v* Ap = (const half8v*)Af + (size_t)mt * Kc * 64 + lane;
    const half8v* Bp = (const half8v*)Wf + lane;
    f32x4 acc[8];
    #pragma unroll
    for (int t = 0; t < 8; ++t) acc[t] = (f32x4){0.f, 0.f, 0.f, 0.f};
    for (int kc = 0; kc < Kc; ++kc) {
        half8v a = Ap[(size_t)kc * 64];
        #pragma unroll
        for (int t = 0; t < 8; ++t) {
            half8v b = Bp[(size_t)(kc * 8 + t) * 64];
            acc[t] = __builtin_amdgcn_mfma_f32_16x16x32_f16(a, b, acc[t], 0, 0, 0);
        }
    }
    int quad = lane >> 4, n15 = lane & 15;
    float bs[8];
    #pragma unroll
    for (int t = 0; t < 8; ++t) bs[t] = bias[t * 16 + n15];

    if (mode == 2) {
        #pragma unroll
        for (int r = 0; r < 4; ++r) {
            int m = mt * 16 + quad * 4 + r;
            float v[8];
            float s = 0.f;
            #pragma unroll
            for (int t = 0; t < 8; ++t) { v[t] = acc[t][r] + bs[t]; s += v[t]; }
            #pragma unroll
            for (int off = 1; off < 16; off <<= 1) s += __shfl_xor(s, off);
            float mu = s * (1.f / 128.f);
            float q = 0.f;
            #pragma unroll
            for (int t = 0; t < 8; ++t) { v[t] -= mu; q += v[t] * v[t]; }
            #pragma unroll
            for (int off = 1; off < 16; off <<= 1) q += __shfl_xor(q, off);
            float rs = rsqrtf(q * (1.f / 128.f) + 1e-5f);
            if (m < Mvalid) {
                #pragma unroll
                for (int t = 0; t < 8; ++t) {
                    int n = t * 16 + n15;
                    float y = v[t] * rs * ln_g[n] + ln_b[n];
                    y = 0.5f * y * (1.f + erff(y * 0.70710678118654752f));
                    out_f16[af_idx(m, n, 4)] = (_Float16)y;
                }
            }
        }
    } else if (mode == 1) {
        #pragma unroll
        for (int r = 0; r < 4; ++r) {
            int m = mt * 16 + quad * 4 + r;
            if (m >= Mvalid) continue;
            #pragma unroll
            for (int t = 0; t < 8; ++t)
                out_f32[(size_t)m * 128 + t * 16 + n15] = acc[t][r] + bs[t];
        }
    } else if (mode == 0) {
        #pragma unroll
        for (int r = 0; r < 4; ++r) {
            int m = mt * 16 + quad * 4 + r;
            if (m >= Mvalid) continue;
            int b = m / NTOT, tok = m - b * NTOT;
            #pragma unroll
            for (int t = 0; t < 8; ++t) {
                int n = t * 16 + n15;
                out_f16[((size_t)(b * 4 + (n >> 5)) * NPAD + tok) * 32 + (n & 31)] =
                    (_Float16)(acc[t][r] + bs[t]);
            }
        }
    } else {
        #pragma unroll
        for (int r = 0; r < 4; ++r) {
            int m = mt * 16 + quad * 4 + r;
            if (m >= Mvalid) continue;
            int b = m / NTOT, tok = m - b * NTOT;
            const float* rp;
            float* dst;
            if (tok < N0) {
                rp = x + ((size_t)b * N0 + tok) * 128;
                dst = out_f32 + ((size_t)b * N0 + tok) * 128;
            } else {
                rp = msg + ((size_t)b * MSGN + (tok - N0)) * 128;
                dst = out_f32 + (size_t)BB * N0 * 128 + ((size_t)b * MSGN + (tok - N0)) * 128;
            }
            #pragma unroll
            for (int t = 0; t < 8; ++t) {
                int n = t * 16 + n15;
                dst[n] = acc[t][r] + bs[t] + rp[n];
            }
        }
    }
}

// ---------------- fused V-fixup + fp16 pack ----------------
__global__ void pack_kv(const float* __restrict__ kv, const float* __restrict__ lcw,
                        const float* __restrict__ lcb, _Float16* __restrict__ Kh,
                        _Float16* __restrict__ Vt, int Wr, int L, int Lm, int Lmp) {
    int idx = blockIdx.x * blockDim.x + threadIdx.x;
    int total = BB * Lmp * 64;
    if (idx >= total) return;
    int ch = idx & 63;
    int rest = idx >> 6;
    int n = rest % Lmp;
    int b = rest / Lmp;
    int h2 = ch >> 5, d = ch & 31;
    int Hr = L / Wr;
    float kval = 0.f, vnew = 0.f;
    if (n < Lm) {
        const float* kvb = kv + (size_t)b * Lm * 128;
        kval = kvb[(size_t)n * 128 + ch];
        float v = kvb[(size_t)n * 128 + 64 + ch];
        float add;
        if (n < L) {
            int hr = n / Wr, wr = n % Wr;
            float sum = lcb[ch];
            #pragma unroll
            for (int ki = 0; ki < 3; ++ki)
                #pragma unroll
                for (int kj = 0; kj < 3; ++kj) {
                    int y = hr + ki - 1, xx = wr + kj - 1;
                    if ((unsigned)y < (unsigned)Hr && (unsigned)xx < (unsigned)Wr)
                        sum += lcw[ch * 9 + ki * 3 + kj] * kvb[((size_t)y * Wr + xx) * 128 + 64 + ch];
                }
            add = sum;
        } else {
            add = v;   // msg tokens: v_add = v => v_new = 2v
        }
        vnew = v + add;
    }
    Kh[((size_t)(b * 2 + h2) * Lmp + n) * 32 + d] = (_Float16)kval;
    Vt[((size_t)(b * 2 + h2) * 32 + d) * Lmp + n] = (_Float16)vnew;
}

// ---------------- MFMA flash attention (register-only) ----------------
__global__ __launch_bounds__(256) void attn_mfma(
    const _Float16* __restrict__ Qh, const _Float16* __restrict__ Kh,
    const _Float16* __restrict__ Vt, _Float16* __restrict__ xcat,
    int Lm, int Lmp, int branch) {
    int tid = threadIdx.x;
    int lane = tid & 63, wave = tid >> 6;
    int b = blockIdx.y, h2 = blockIdx.z;
    int tile = blockIdx.x * 4 + wave;
    if (tile >= QTILES) return;
    int n0 = tile * 16;
    int q16 = lane & 15, quad = lane >> 4;
    int hg = branch * 2 + h2;

    half8v qf = *(const half8v*)(Qh + ((size_t)(b * 4 + hg) * NPAD + n0 + q16) * 32 + quad * 8);
    const _Float16* kb = Kh + (size_t)(b * 2 + h2) * Lmp * 32;
    const _Float16* vb = Vt + (size_t)(b * 2 + h2) * 32 * Lmp;

    f32x4 O0 = {0.f, 0.f, 0.f, 0.f}, O1 = {0.f, 0.f, 0.f, 0.f};
    float m_run = -1e30f, l_part = 0.f;
    const float scale = 0.17677669529663687f;
    const f32x4 zf = {0.f, 0.f, 0.f, 0.f};

    for (int k0 = 0; k0 < Lmp; k0 += 16) {
        half8v kf = *(const half8v*)(kb + (size_t)(k0 + q16) * 32 + quad * 8);
        f32x4 s4 = __builtin_amdgcn_mfma_f32_16x16x32_f16(kf, qf, zf, 0, 0, 0);
        float sc[4];
        #pragma unroll
        for (int r = 0; r < 4; ++r) {
            int key = k0 + quad * 4 + r;
            sc[r] = (key < Lm) ? s4[r] * scale : -1e30f;
        }
        float mx = fmaxf(fmaxf(sc[0], sc[1]), fmaxf(sc[2], sc[3]));
        mx = fmaxf(mx, __shfl_xor(mx, 16));
        mx = fmaxf(mx, __shfl_xor(mx, 32));
        float mnew = fmaxf(m_run, mx);
        float alpha = __expf(m_run - mnew);
        m_run = mnew;
        float p[4];
        #pragma unroll
        for (int r = 0; r < 4; ++r) p[r] = __expf(sc[r] - mnew);
        l_part = l_part * alpha + p[0] + p[1] + p[2] + p[3];
        half4v pf;
        #pragma unroll
        for (int r = 0; r < 4; ++r) pf[r] = (_Float16)p[r];
        int kq = k0 + quad * 4;
        half4v v0 = *(const half4v*)(vb + (size_t)q16 * Lmp + kq);
        half4v v1 = *(const half4v*)(vb + (size_t)(16 + q16) * Lmp + kq);
        #pragma unroll
        for (int r = 0; r < 4; ++r) {
            float ar = __shfl(alpha, quad * 4 + r);
            O0[r] *= ar;
            O1[r] *= ar;
        }
        O0 = __builtin_amdgcn_mfma_f32_16x16x16f16(pf, v0, O0, 0, 0, 0);
        O1 = __builtin_amdgcn_mfma_f32_16x16x16f16(pf, v1, O1, 0, 0, 0);
    }

    float l = l_part;
    l += __shfl_xor(l, 16);
    l += __shfl_xor(l, 32);
    float invl = 1.f / l;
    int kbase = branch * 64 + h2 * 32;
    #pragma unroll
    for (int r = 0; r < 4; ++r) {
        float ir = __shfl(invl, quad * 4 + r);
        int n = n0 + quad * 4 + r;
        if (n < NTOT) {
            int m = b * NTOT + n;
            xcat[af_idx(m, kbase + q16, 4)] = (_Float16)(O0[r] * ir);
            xcat[af_idx(m, kbase + 16 + q16, 4)] = (_Float16)(O1[r] * ir);
        }
    }
}

extern "C" void kernel_launch(void* const* d_in, const int* in_sizes, int n_in,
                              void* d_out, int out_size, void* d_ws, size_t ws_size,
                              hipStream_t stream) {
    const float* x     = (const float*)d_in[0];
    const float* msg   = (const float*)d_in[1];
    const float* Wq    = (const float*)d_in[2];
    const float* bq    = (const float*)d_in[3];
    const float* sr1w  = (const float*)d_in[4];
    const float* sr1b  = (const float*)d_in[5];
    const float* ln1g  = (const float*)d_in[6];
    const float* ln1b  = (const float*)d_in[7];
    const float* sr2w  = (const float*)d_in[8];
    const float* sr2b  = (const float*)d_in[9];
    const float* ln2g  = (const float*)d_in[10];
    const float* ln2b  = (const float*)d_in[11];
    const float* kv1w  = (const float*)d_in[12];
    const float* kv1b  = (const float*)d_in[13];
    const float* kv2w  = (const float*)d_in[14];
    const float* kv2b  = (const float*)d_in[15];
    const float* lc1w  = (const float*)d_in[16];
    const float* lc1b  = (const float*)d_in[17];
    const float* lc2w  = (const float*)d_in[18];
    const float* lc2b  = (const float*)d_in[19];
    const float* projw = (const float*)d_in[20];
    const float* projb = (const float*)d_in[21];
    float* ws  = (float*)d_ws;
    float* out = (float*)d_out;

    _Float16* WfQ    = (_Float16*)(ws + OFF_WFQ);
    _Float16* WfKV1  = (_Float16*)(ws + OFF_WFKV1);
    _Float16* WfKV2  = (_Float16*)(ws + OFF_WFKV2);
    _Float16* WfPROJ = (_Float16*)(ws + OFF_WFPROJ);
    _Float16* WfSR1  = (_Float16*)(ws + OFF_WFSR1);
    _Float16* WfSR2  = (_Float16*)(ws + OFF_WFSR2);
    _Float16* Qh     = (_Float16*)(ws + OFF_QH);
    _Float16* XA     = (_Float16*)(ws + OFF_XA);    // qproj input, later attn output
    _Float16* XIM    = (_Float16*)(ws + OFF_XIM);
    _Float16* XK1    = (_Float16*)(ws + OFF_XK1);
    _Float16* XK2    = (_Float16*)(ws + OFF_XK2);
    float* kv1o      = ws + OFF_KV1O;
    float* kv2o      = ws + OFF_KV2O;
    _Float16* Kh1    = (_Float16*)(ws + OFF_KH1);
    _Float16* Vt1    = (_Float16*)(ws + OFF_VT1);
    _Float16* Kh2    = (_Float16*)(ws + OFF_KH2);
    _Float16* Vt2    = (_Float16*)(ws + OFF_VT2);

    prep_weights<<<192, 256, 0, stream>>>(Wq, kv1w, kv2w, projw, sr1w, sr2w, ws);
    zero_qpad<<<48, 256, 0, stream>>>(Qh);
    convert_x<<<2052, 256, 0, stream>>>(x, msg, XA);

    // q projection: M=32800, K=128 -> Qh fp16
    gemm_mfma<<<513, 256, 0, stream>>>(XA, WfQ, bq, 128, BB * NTOT, 0,
                                       nullptr, Qh, nullptr, nullptr, nullptr, nullptr);

    // ---- branch 1 (stride 4, L=256, Lm=260, Lmp=272, K=2048) ----
    im2col<<<2112, 256, 0, stream>>>(x, msg, XIM, 4, 16, 256, 260, 64, 540672);
    gemm_mfma<<<33, 256, 0, stream>>>(XIM, WfSR1, sr1b, 2048, BB * 260, 2,
                                      nullptr, XK1, ln1g, ln1b, nullptr, nullptr);
    gemm_mfma<<<33, 256, 0, stream>>>(XK1, WfKV1, kv1b, 128, BB * 260, 1,
                                      kv1o, nullptr, nullptr, nullptr, nullptr, nullptr);
    pack_kv<<<544, 256, 0, stream>>>(kv1o, lc1w, lc1b, Kh1, Vt1, 16, 256, 260, 272);
    attn_mfma<<<dim3(65, 8, 2), 256, 0, stream>>>(Qh, Kh1, Vt1, XA, 260, 272, 0);

    // ---- branch 2 (stride 2, L=1024, Lm=1028, Lmp=1040, K=512) ----
    im2col<<<2064, 256, 0, stream>>>(x, msg, XIM, 2, 32, 1024, 1028, 16, 528384);
    gemm_mfma<<<129, 256, 0, stream>>>(XIM, WfSR2, sr2b, 512, BB * 1028, 2,
                                       nullptr, XK2, ln2g, ln2b, nullptr, nullptr);
    gemm_mfma<<<129, 256, 0, stream>>>(XK2, WfKV2, kv2b, 128, BB * 1028, 1,
                                       kv2o, nullptr, nullptr, nullptr, nullptr, nullptr);
    pack_kv<<<2080, 256, 0, stream>>>(kv2o, lc2w, lc2b, Kh2, Vt2, 32, 1024, 1028, 1040);
    attn_mfma<<<dim3(65, 8, 2), 256, 0, stream>>>(Qh, Kh2, Vt2, XA, 1028, 1040, 1);

    // final projection + residual -> d_out (split)
    gemm_mfma<<<513, 256, 0, stream>>>(XA, WfPROJ, projb, 128, BB * NTOT, 3,
                                       out, nullptr, nullptr, nullptr, x, msg);
}